// Round 4
// baseline (276.803 us; speedup 1.0000x reference)
//
#include <hip/hip_runtime.h>
#include <hip/hip_bf16.h>

#define NB 2
#define NS 2048
#define ND 1024
#define NH 16
#define NDH 64
#define NM 4096   // NB*NS

typedef __bf16 bf16;
typedef __bf16 bf16x8 __attribute__((ext_vector_type(8)));
typedef __bf16 bf16x4 __attribute__((ext_vector_type(4)));
typedef float f32x4 __attribute__((ext_vector_type(4)));
typedef float f32x16 __attribute__((ext_vector_type(16)));

#define ASYNC16(g, l) __builtin_amdgcn_global_load_lds( \
    (const __attribute__((address_space(1))) void*)(g), \
    (__attribute__((address_space(3))) void*)(l), 16, 0, 0)

static __device__ __forceinline__ unsigned cvt_pk_bf16(float a, float b) {
  unsigned r;
  asm("v_cvt_pk_bf16_f32 %0, %1, %2" : "=v"(r) : "v"(a), "v"(b));
  return r;
}

// ---------------------------------------------------------------- convert
__global__ __launch_bounds__(256) void convert_kernel(
    const float* __restrict__ x,
    const float* __restrict__ wq, const float* __restrict__ wk,
    const float* __restrict__ wv, const float* __restrict__ wo,
    bf16* __restrict__ xb, bf16* __restrict__ wb) {
  int i = blockIdx.x * 256 + threadIdx.x;   // float4 index
  const int n_x4 = (NM * ND) / 4;           // 1M
  const int n_w4 = (ND * ND) / 4;           // 256K
  float4 v;
  bf16* dst;
  if (i < n_x4) {
    v = ((const float4*)x)[i];
    dst = xb + (size_t)i * 4;
  } else {
    int j = i - n_x4;
    int w = j / n_w4;
    int o = j - w * n_w4;
    const float* W = (w == 0) ? wq : (w == 1) ? wk : (w == 2) ? wv : wo;
    v = ((const float4*)W)[o];
    dst = wb + (size_t)w * (ND * ND) + (size_t)o * 4;
  }
  bf16x4 o4;
  o4[0] = (bf16)v.x; o4[1] = (bf16)v.y; o4[2] = (bf16)v.z; o4[3] = (bf16)v.w;
  *(bf16x4*)dst = o4;
}

// ---------------------------------------------------------------- rope table
// tab[s*32+d] = {cos(s*invf(d)), sin(s*invf(d))}, d in [0,32)
__global__ __launch_bounds__(256) void tab_kernel(float2* __restrict__ tab) {
  int t = blockIdx.x * 256 + threadIdx.x;   // 65536
  int s = t >> 5, d = t & 31;
  float invf = exp2f(-0.4152410118609203f * (float)d);  // 10000^(-d/32)
  float f = (float)s * invf;
  float sn, cs;
  sincosf(f, &sn, &cs);
  tab[t] = make_float2(cs, sn);
}

// ---------------------------------------------------------------- gemm QKV
// C[M,N] = A[M,K] * B[N,K]^T per z in {Q,K,V}; RoPE fused for z<2.
// Q is additionally scaled by 0.125*log2(e) so attention can use exp2.
__global__ __launch_bounds__(256) void gemm_qkv(
    const bf16* __restrict__ A, const bf16* __restrict__ Bmat,
    bf16* __restrict__ Qr, bf16* __restrict__ Kr, bf16* __restrict__ vraw,
    const float2* __restrict__ tab) {
  __shared__ bf16 As[128 * 64];
  __shared__ bf16 Bs[128 * 64];
  const int t = threadIdx.x;
  const int lane = t & 63, w = t >> 6;
  const int wr = w >> 1, wc = w & 1;
  const int bm = blockIdx.y * 128;
  const int bn = blockIdx.x * 128;
  const int z = blockIdx.z;
  const bf16* Bz = Bmat + (size_t)z * ND * ND;

  f32x4 acc[4][4];
#pragma unroll
  for (int i = 0; i < 4; ++i)
#pragma unroll
    for (int j = 0; j < 4; ++j) acc[i][j] = (f32x4){0.f, 0.f, 0.f, 0.f};

  for (int kt = 0; kt < ND / 64; ++kt) {
    __syncthreads();
#pragma unroll
    for (int i = 0; i < 4; ++i) {
      int c = w * 64 + lane + i * 256;
      int row = c >> 3;
      int js = (c & 7) ^ (row & 7);
      ASYNC16(A + (size_t)(bm + row) * ND + kt * 64 + js * 8, As + c * 8);
      ASYNC16(Bz + (size_t)(bn + row) * ND + kt * 64 + js * 8, Bs + c * 8);
    }
    __syncthreads();
#pragma unroll
    for (int ks = 0; ks < 2; ++ks) {
      const int kb = ks * 64 + (lane >> 4) * 16;
      bf16x8 af[4], bfr[4];
#pragma unroll
      for (int i = 0; i < 4; ++i) {
        int ra = wr * 64 + i * 16 + (lane & 15);
        af[i] = *(const bf16x8*)((const char*)As + ra * 128 + (kb ^ ((ra & 7) << 4)));
        int rb = wc * 64 + i * 16 + (lane & 15);
        bfr[i] = *(const bf16x8*)((const char*)Bs + rb * 128 + (kb ^ ((rb & 7) << 4)));
      }
#pragma unroll
      for (int i = 0; i < 4; ++i)
#pragma unroll
        for (int j = 0; j < 4; ++j)
          acc[i][j] = __builtin_amdgcn_mfma_f32_16x16x32_bf16(af[i], bfr[j], acc[i][j], 0, 0, 0);
    }
  }

  const int row0 = bm + wr * 64;
  const int col0 = bn + wc * 64;
  if (z == 2) {
#pragma unroll
    for (int i = 0; i < 4; ++i)
#pragma unroll
      for (int j = 0; j < 4; ++j) {
        int r = row0 + i * 16 + (lane >> 4) * 4;
        int ccol = col0 + j * 16 + (lane & 15);
#pragma unroll
        for (int q = 0; q < 4; ++q)
          vraw[(size_t)(r + q) * ND + ccol] = (bf16)acc[i][j][q];
      }
  } else {
    bf16* dst = z ? Kr : Qr;
    const float qs = z ? 1.0f : 0.1803368801111204f;  // 0.125*log2(e) for Q
    const int h = col0 >> 6;
    const int ln15 = lane & 15;
#pragma unroll
    for (int i = 0; i < 4; ++i)
#pragma unroll
      for (int j = 0; j < 2; ++j)
#pragma unroll
        for (int q = 0; q < 4; ++q) {
          int r = row0 + i * 16 + (lane >> 4) * 4 + q;
          int b = r >> 11, s = r & (NS - 1);
          int d1 = j * 16 + ln15;
          float2 tc = tab[s * 32 + d1];
          float x1 = acc[i][j][q], x2 = acc[i][j + 2][q];
          size_t base = ((size_t)((b * NH + h) * NS + s)) * NDH;
          dst[base + d1]      = (bf16)((x1 * tc.x - x2 * tc.y) * qs);
          dst[base + d1 + 32] = (bf16)((x2 * tc.x + x1 * tc.y) * qs);
        }
  }
}

// ---------------------------------------------------------------- gemm out
// out[M,N] = A[M,K] * Wo[N,K]^T, fp32 output
__global__ __launch_bounds__(256) void gemm_out(
    const bf16* __restrict__ A, const bf16* __restrict__ Bmat,
    float* __restrict__ Cout) {
  __shared__ bf16 As[128 * 64];
  __shared__ bf16 Bs[128 * 64];
  const int t = threadIdx.x;
  const int lane = t & 63, w = t >> 6;
  const int wr = w >> 1, wc = w & 1;
  const int bm = blockIdx.y * 128;
  const int bn = blockIdx.x * 128;

  f32x4 acc[4][4];
#pragma unroll
  for (int i = 0; i < 4; ++i)
#pragma unroll
    for (int j = 0; j < 4; ++j) acc[i][j] = (f32x4){0.f, 0.f, 0.f, 0.f};

  for (int kt = 0; kt < ND / 64; ++kt) {
    __syncthreads();
#pragma unroll
    for (int i = 0; i < 4; ++i) {
      int c = w * 64 + lane + i * 256;
      int row = c >> 3;
      int js = (c & 7) ^ (row & 7);
      ASYNC16(A + (size_t)(bm + row) * ND + kt * 64 + js * 8, As + c * 8);
      ASYNC16(Bmat + (size_t)(bn + row) * ND + kt * 64 + js * 8, Bs + c * 8);
    }
    __syncthreads();
#pragma unroll
    for (int ks = 0; ks < 2; ++ks) {
      const int kb = ks * 64 + (lane >> 4) * 16;
      bf16x8 af[4], bfr[4];
#pragma unroll
      for (int i = 0; i < 4; ++i) {
        int ra = wr * 64 + i * 16 + (lane & 15);
        af[i] = *(const bf16x8*)((const char*)As + ra * 128 + (kb ^ ((ra & 7) << 4)));
        int rb = wc * 64 + i * 16 + (lane & 15);
        bfr[i] = *(const bf16x8*)((const char*)Bs + rb * 128 + (kb ^ ((rb & 7) << 4)));
      }
#pragma unroll
      for (int i = 0; i < 4; ++i)
#pragma unroll
        for (int j = 0; j < 4; ++j)
          acc[i][j] = __builtin_amdgcn_mfma_f32_16x16x32_bf16(af[i], bfr[j], acc[i][j], 0, 0, 0);
    }
  }

  const int row0 = bm + wr * 64;
  const int col0 = bn + wc * 64;
#pragma unroll
  for (int i = 0; i < 4; ++i)
#pragma unroll
    for (int j = 0; j < 4; ++j) {
      int r = row0 + i * 16 + (lane >> 4) * 4;
      int ccol = col0 + j * 16 + (lane & 15);
#pragma unroll
      for (int q = 0; q < 4; ++q)
        Cout[(size_t)(r + q) * ND + ccol] = acc[i][j][q];
    }
}

// ---------------------------------------------------------------- V^T
// vraw bf16 [NM, ND] -> VT bf16 [B,H,Dh,S]
__global__ __launch_bounds__(256) void transv_kernel(
    const bf16* __restrict__ vraw, bf16* __restrict__ VT) {
  __shared__ bf16 tl[64][65];
  int s0 = blockIdx.x * 64;
  int bh = blockIdx.y;
  int b = bh >> 4, h = bh & 15;
  int t = threadIdx.x;
#pragma unroll
  for (int i = 0; i < 4; ++i) {
    int row = (t >> 4) + i * 16;
    int d4 = (t & 15) * 4;
    *(bf16x4*)&tl[row][d4] =
        *(const bf16x4*)&vraw[((size_t)(b * NS + s0 + row)) * ND + h * NDH + d4];
  }
  __syncthreads();
#pragma unroll
  for (int i = 0; i < 4; ++i) {
    int dr = (t >> 4) + i * 16;
    int s4 = (t & 15) * 4;
    bf16x4 o;
    o[0] = tl[s4 + 0][dr]; o[1] = tl[s4 + 1][dr];
    o[2] = tl[s4 + 2][dr]; o[3] = tl[s4 + 3][dr];
    *(bf16x4*)&VT[((size_t)(bh * NDH + dr)) * NS + s0 + s4] = o;
  }
}

// ---------------------------------------------------------------- attention
// Swapped-QK (mfma(K,Q)) in-register-softmax flash attention.
// NO LDS, NO BARRIERS: K/V MFMA fragments read directly from global
// (L1/L2-resident; all 8 waves/CU share the same tile bytes).
// 4 waves x 32 q-rows, KVBLK=64.  Qr pre-scaled by 0.125*log2e -> exp2 domain.
// Score C-layout: col=lane&31=query, row=(reg&3)+8*(reg>>2)+4*(lane>>5)=key.
__global__ __launch_bounds__(256, 2) void attn_kernel(
    const bf16* __restrict__ Qr, const bf16* __restrict__ Kr,
    const bf16* __restrict__ VT, bf16* __restrict__ out) {
  const int t = threadIdx.x, lane = t & 63, w = t >> 6;
  const int hi = lane >> 5, ln = lane & 31;
  // XCD-bijective swizzle (512 blocks, 512%8==0): 4 bh per XCD -> K/V L2-resident
  int wg = blockIdx.x;
  int sw = (wg & 7) * 64 + (wg >> 3);
  const int qb = sw & 15, bh = sw >> 4;
  const int q0 = qb * 128 + w * 32;

  // Q fragment: B-operand, col=query=ln, k=d=(hi*8+e)+16c
  bf16x8 qv[4];
  {
    const bf16* Qb = Qr + ((size_t)bh * NS + q0 + ln) * NDH + hi * 8;
#pragma unroll
    for (int c = 0; c < 4; ++c) qv[c] = *(const bf16x8*)(Qb + c * 16);
  }

  // direct-global fragment base pointers (advance by const per kt)
  const bf16* kp0 = Kr + ((size_t)bh * NS + ln) * NDH + hi * 8;        // keys ln
  const bf16* kp1 = kp0 + (size_t)32 * NDH;                            // keys 32+ln
  const bf16* vp0 = VT + ((size_t)bh * NDH + ln) * NS + hi * 8;        // d = ln
  const bf16* vp1 = vp0 + (size_t)32 * NS;                             // d = 32+ln

  f32x16 O0, O1;
#pragma unroll
  for (int r = 0; r < 16; ++r) { O0[r] = 0.f; O1[r] = 0.f; }
  float m = -1e30f, l = 0.f;

  for (int kt = 0; kt < NS / 64; ++kt) {
    // S = K Q^T (swapped): lane owns full 64-key row for query ln (pair lane^32)
    f32x16 s0, s1;
#pragma unroll
    for (int r = 0; r < 16; ++r) { s0[r] = 0.f; s1[r] = 0.f; }
    bf16x8 k0[4], k1[4];
#pragma unroll
    for (int c = 0; c < 4; ++c) {
      k0[c] = *(const bf16x8*)(kp0 + c * 16);
      k1[c] = *(const bf16x8*)(kp1 + c * 16);
    }
#pragma unroll
    for (int c = 0; c < 4; ++c) {
      s0 = __builtin_amdgcn_mfma_f32_32x32x16_bf16(k0[c], qv[c], s0, 0, 0, 0);
      s1 = __builtin_amdgcn_mfma_f32_32x32x16_bf16(k1[c], qv[c], s1, 0, 0, 0);
    }

    // row max: pairwise tree + one half-swap
    float a0[8];
#pragma unroll
    for (int r = 0; r < 8; ++r) a0[r] = fmaxf(fmaxf(s0[r], s0[r + 8]), fmaxf(s1[r], s1[r + 8]));
    float b0 = fmaxf(fmaxf(a0[0], a0[1]), fmaxf(a0[2], a0[3]));
    float b1 = fmaxf(fmaxf(a0[4], a0[5]), fmaxf(a0[6], a0[7]));
    float pmax = fmaxf(b0, b1);
    pmax = fmaxf(pmax, __shfl_xor(pmax, 32, 64));

    // defer-max (T13): rescale only when max grew past threshold (log2 units)
    if (!__all(pmax - m <= 8.0f)) {
      float mnew = fmaxf(m, pmax);
      float scl = exp2f(m - mnew);
      m = mnew; l *= scl;
#pragma unroll
      for (int r = 0; r < 16; ++r) { O0[r] *= scl; O1[r] *= scl; }
    }

    // P = exp2(S - m), tree sum
    float p0[16], p1[16];
#pragma unroll
    for (int r = 0; r < 16; ++r) { p0[r] = exp2f(s0[r] - m); p1[r] = exp2f(s1[r] - m); }
    float sp[8];
#pragma unroll
    for (int r = 0; r < 8; ++r) sp[r] = (p0[r] + p0[r + 8]) + (p1[r] + p1[r + 8]);
    float sum = (((sp[0] + sp[1]) + (sp[2] + sp[3])) + ((sp[4] + sp[5]) + (sp[6] + sp[7])));
    sum += __shfl_xor(sum, 32, 64);
    l += sum;

    // P -> bf16 A-fragments in-register (T12): pack pairs, swap halves
    unsigned u0[8], u1[8], x0[8], x1[8];
#pragma unroll
    for (int g = 0; g < 4; ++g) {
      u0[g]     = cvt_pk_bf16(p0[4 * g],     p0[4 * g + 1]);
      u1[g]     = cvt_pk_bf16(p0[4 * g + 2], p0[4 * g + 3]);
      u0[4 + g] = cvt_pk_bf16(p1[4 * g],     p1[4 * g + 1]);
      u1[4 + g] = cvt_pk_bf16(p1[4 * g + 2], p1[4 * g + 3]);
    }
#pragma unroll
    for (int g = 0; g < 8; ++g) {
      x0[g] = __shfl_xor(u0[g], 32, 64);
      x1[g] = __shfl_xor(u1[g], 32, 64);
    }

    // O += P V   (A=P row=query, k=key; B=VT rows=d, direct from global)
    bf16x8 v0[4], v1[4];
#pragma unroll
    for (int c = 0; c < 4; ++c) {
      v0[c] = *(const bf16x8*)(vp0 + c * 16);
      v1[c] = *(const bf16x8*)(vp1 + c * 16);
    }
#pragma unroll
    for (int c = 0; c < 4; ++c) {
      int base = (c >> 1) * 4 + (c & 1) * 2;   // kk*4 + even-group
      union { unsigned u[4]; bf16x8 v; } pa;
      pa.u[0] = hi ? x0[base + 1] : u0[base];
      pa.u[1] = hi ? x1[base + 1] : u1[base];
      pa.u[2] = hi ? u0[base + 1] : x0[base];
      pa.u[3] = hi ? u1[base + 1] : x1[base];
      O0 = __builtin_amdgcn_mfma_f32_32x32x16_bf16(pa.v, v0[c], O0, 0, 0, 0);
      O1 = __builtin_amdgcn_mfma_f32_32x32x16_bf16(pa.v, v1[c], O1, 0, 0, 0);
    }

    kp0 += (size_t)64 * NDH; kp1 += (size_t)64 * NDH;   // next 64 keys
    vp0 += 64;               vp1 += 64;
  }

  // epilogue: O row=query=(reg&3)+8*(reg>>2)+4*hi, col=d (O0: d=ln, O1: d=32+ln)
  float rl = 1.0f / l;
  const int b = bh >> 4, h = bh & 15;
#pragma unroll
  for (int r = 0; r < 16; ++r) {
    int q = (r & 3) + 8 * (r >> 2) + 4 * hi;
    float rlq = __shfl(rl, q, 64);
    int s = q0 + q;
    size_t base = ((size_t)(b * NS + s)) * ND + h * NDH + ln;
    out[base]      = (bf16)(O0[r] * rlq);
    out[base + 32] = (bf16)(O1[r] * rlq);
  }
}

// ---------------------------------------------------------------- launch
extern "C" void kernel_launch(void* const* d_in, const int* in_sizes, int n_in,
                              void* d_out, int out_size, void* d_ws, size_t ws_size,
                              hipStream_t stream) {
  const float* x  = (const float*)d_in[0];
  const float* wq = (const float*)d_in[1];
  const float* wk = (const float*)d_in[2];
  const float* wv = (const float*)d_in[3];
  const float* wo = (const float*)d_in[4];
  char* ws = (char*)d_ws;
  bf16* xb    = (bf16*)(ws);                     // 8MB [4096,1024]
  bf16* wb    = (bf16*)(ws + (8u << 20));        // 8MB Wq|Wk|Wv|Wo
  bf16* vraw  = (bf16*)(ws + (16u << 20));       // 8MB [4096,1024]
  bf16* Qr    = (bf16*)(ws + (24u << 20));       // 8MB [B,H,S,Dh] (pre-scaled)
  bf16* Kr    = (bf16*)(ws + (32u << 20));       // 8MB [B,H,S,Dh]
  bf16* VT    = (bf16*)(ws + (40u << 20));       // 8MB [B,H,Dh,S]
  bf16* attnb = (bf16*)(ws + (48u << 20));       // 8MB [B,S,H*Dh]
  float2* tab = (float2*)(ws + (56u << 20));     // 512KB [2048][32]
  float* out  = (float*)d_out;

  convert_kernel<<<8192, 256, 0, stream>>>(x, wq, wk, wv, wo, xb, wb);
  tab_kernel<<<256, 256, 0, stream>>>(tab);
  gemm_qkv<<<dim3(8, 32, 3), 256, 0, stream>>>(xb, wb, Qr, Kr, vraw, tab);
  transv_kernel<<<dim3(32, 32), 256, 0, stream>>>(vraw, VT);
  attn_kernel<<<dim3(512), 256, 0, stream>>>(Qr, Kr, VT, attnb);
  gemm_out<<<dim3(8, 32), 256, 0, stream>>>(attnb, wb + 3 * ND * ND, out);
}

// Round 5
// 224.421 us; speedup vs baseline: 1.2334x; 1.2334x over previous
//
#include <hip/hip_runtime.h>
#include <hip/hip_bf16.h>

#define NB 2
#define NS 2048
#define ND 1024
#define NH 16
#define NDH 64
#define NM 4096   // NB*NS

typedef __bf16 bf16;
typedef __bf16 bf16x8 __attribute__((ext_vector_type(8)));
typedef __bf16 bf16x4 __attribute__((ext_vector_type(4)));
typedef float f32x4 __attribute__((ext_vector_type(4)));
typedef float f32x16 __attribute__((ext_vector_type(16)));

#define ASYNC16(g, l) __builtin_amdgcn_global_load_lds( \
    (const __attribute__((address_space(1))) void*)(g), \
    (__attribute__((address_space(3))) void*)(l), 16, 0, 0)

static __device__ __forceinline__ unsigned cvt_pk_bf16(float a, float b) {
  unsigned r;
  asm("v_cvt_pk_bf16_f32 %0, %1, %2" : "=v"(r) : "v"(a), "v"(b));
  return r;
}

// ---------------------------------------------------------------- convert
__global__ __launch_bounds__(256) void convert_kernel(
    const float* __restrict__ x,
    const float* __restrict__ wq, const float* __restrict__ wk,
    const float* __restrict__ wv, const float* __restrict__ wo,
    bf16* __restrict__ xb, bf16* __restrict__ wb) {
  int i = blockIdx.x * 256 + threadIdx.x;   // float4 index
  const int n_x4 = (NM * ND) / 4;           // 1M
  const int n_w4 = (ND * ND) / 4;           // 256K
  float4 v;
  bf16* dst;
  if (i < n_x4) {
    v = ((const float4*)x)[i];
    dst = xb + (size_t)i * 4;
  } else {
    int j = i - n_x4;
    int w = j / n_w4;
    int o = j - w * n_w4;
    const float* W = (w == 0) ? wq : (w == 1) ? wk : (w == 2) ? wv : wo;
    v = ((const float4*)W)[o];
    dst = wb + (size_t)w * (ND * ND) + (size_t)o * 4;
  }
  bf16x4 o4;
  o4[0] = (bf16)v.x; o4[1] = (bf16)v.y; o4[2] = (bf16)v.z; o4[3] = (bf16)v.w;
  *(bf16x4*)dst = o4;
}

// ---------------------------------------------------------------- rope table
// tab[s*32+d] = {cos(s*invf(d)), sin(s*invf(d))}, d in [0,32)
__global__ __launch_bounds__(256) void tab_kernel(float2* __restrict__ tab) {
  int t = blockIdx.x * 256 + threadIdx.x;   // 65536
  int s = t >> 5, d = t & 31;
  float invf = exp2f(-0.4152410118609203f * (float)d);  // 10000^(-d/32)
  float f = (float)s * invf;
  float sn, cs;
  sincosf(f, &sn, &cs);
  tab[t] = make_float2(cs, sn);
}

// ---------------------------------------------------------------- gemm QKV
// C[M,N] = A[M,K] * B[N,K]^T per z in {Q,K,V}; RoPE fused for z<2.
// Q is additionally scaled by 0.125*log2(e) so attention can use exp2.
__global__ __launch_bounds__(256) void gemm_qkv(
    const bf16* __restrict__ A, const bf16* __restrict__ Bmat,
    bf16* __restrict__ Qr, bf16* __restrict__ Kr, bf16* __restrict__ vraw,
    const float2* __restrict__ tab) {
  __shared__ bf16 As[128 * 64];
  __shared__ bf16 Bs[128 * 64];
  const int t = threadIdx.x;
  const int lane = t & 63, w = t >> 6;
  const int wr = w >> 1, wc = w & 1;
  const int bm = blockIdx.y * 128;
  const int bn = blockIdx.x * 128;
  const int z = blockIdx.z;
  const bf16* Bz = Bmat + (size_t)z * ND * ND;

  f32x4 acc[4][4];
#pragma unroll
  for (int i = 0; i < 4; ++i)
#pragma unroll
    for (int j = 0; j < 4; ++j) acc[i][j] = (f32x4){0.f, 0.f, 0.f, 0.f};

  for (int kt = 0; kt < ND / 64; ++kt) {
    __syncthreads();
#pragma unroll
    for (int i = 0; i < 4; ++i) {
      int c = w * 64 + lane + i * 256;
      int row = c >> 3;
      int js = (c & 7) ^ (row & 7);
      ASYNC16(A + (size_t)(bm + row) * ND + kt * 64 + js * 8, As + c * 8);
      ASYNC16(Bz + (size_t)(bn + row) * ND + kt * 64 + js * 8, Bs + c * 8);
    }
    __syncthreads();
#pragma unroll
    for (int ks = 0; ks < 2; ++ks) {
      const int kb = ks * 64 + (lane >> 4) * 16;
      bf16x8 af[4], bfr[4];
#pragma unroll
      for (int i = 0; i < 4; ++i) {
        int ra = wr * 64 + i * 16 + (lane & 15);
        af[i] = *(const bf16x8*)((const char*)As + ra * 128 + (kb ^ ((ra & 7) << 4)));
        int rb = wc * 64 + i * 16 + (lane & 15);
        bfr[i] = *(const bf16x8*)((const char*)Bs + rb * 128 + (kb ^ ((rb & 7) << 4)));
      }
#pragma unroll
      for (int i = 0; i < 4; ++i)
#pragma unroll
        for (int j = 0; j < 4; ++j)
          acc[i][j] = __builtin_amdgcn_mfma_f32_16x16x32_bf16(af[i], bfr[j], acc[i][j], 0, 0, 0);
    }
  }

  const int row0 = bm + wr * 64;
  const int col0 = bn + wc * 64;
  if (z == 2) {
#pragma unroll
    for (int i = 0; i < 4; ++i)
#pragma unroll
      for (int j = 0; j < 4; ++j) {
        int r = row0 + i * 16 + (lane >> 4) * 4;
        int ccol = col0 + j * 16 + (lane & 15);
#pragma unroll
        for (int q = 0; q < 4; ++q)
          vraw[(size_t)(r + q) * ND + ccol] = (bf16)acc[i][j][q];
      }
  } else {
    bf16* dst = z ? Kr : Qr;
    const float qs = z ? 1.0f : 0.1803368801111204f;  // 0.125*log2(e) for Q
    const int h = col0 >> 6;
    const int ln15 = lane & 15;
#pragma unroll
    for (int i = 0; i < 4; ++i)
#pragma unroll
      for (int j = 0; j < 2; ++j)
#pragma unroll
        for (int q = 0; q < 4; ++q) {
          int r = row0 + i * 16 + (lane >> 4) * 4 + q;
          int b = r >> 11, s = r & (NS - 1);
          int d1 = j * 16 + ln15;
          float2 tc = tab[s * 32 + d1];
          float x1 = acc[i][j][q], x2 = acc[i][j + 2][q];
          size_t base = ((size_t)((b * NH + h) * NS + s)) * NDH;
          dst[base + d1]      = (bf16)((x1 * tc.x - x2 * tc.y) * qs);
          dst[base + d1 + 32] = (bf16)((x2 * tc.x + x1 * tc.y) * qs);
        }
  }
}

// ---------------------------------------------------------------- gemm out
// out[M,N] = A[M,K] * Wo[N,K]^T, fp32 output.  BM=128, BN=64 -> 512 blocks
// (2 blocks/CU; the 256-block version exposed the full barrier drain).
__global__ __launch_bounds__(256) void gemm_out(
    const bf16* __restrict__ A, const bf16* __restrict__ Bmat,
    float* __restrict__ Cout) {
  __shared__ bf16 As[128 * 64];
  __shared__ bf16 Bs[64 * 64];
  const int t = threadIdx.x;
  const int lane = t & 63, w = t >> 6;
  const int wr = w >> 1, wc = w & 1;
  const int bm = blockIdx.y * 128;
  const int bn = blockIdx.x * 64;

  f32x4 acc[4][2];
#pragma unroll
  for (int i = 0; i < 4; ++i)
#pragma unroll
    for (int j = 0; j < 2; ++j) acc[i][j] = (f32x4){0.f, 0.f, 0.f, 0.f};

  for (int kt = 0; kt < ND / 64; ++kt) {
    __syncthreads();
#pragma unroll
    for (int i = 0; i < 4; ++i) {
      int c = i * 256 + t;
      int row = c >> 3;
      int js = (c & 7) ^ (row & 7);
      ASYNC16(A + (size_t)(bm + row) * ND + kt * 64 + js * 8, As + c * 8);
    }
#pragma unroll
    for (int i = 0; i < 2; ++i) {
      int c = i * 256 + t;
      int row = c >> 3;
      int js = (c & 7) ^ (row & 7);
      ASYNC16(Bmat + (size_t)(bn + row) * ND + kt * 64 + js * 8, Bs + c * 8);
    }
    __syncthreads();
#pragma unroll
    for (int ks = 0; ks < 2; ++ks) {
      const int kb = ks * 64 + (lane >> 4) * 16;
      bf16x8 af[4], bfr[2];
#pragma unroll
      for (int i = 0; i < 4; ++i) {
        int ra = wr * 64 + i * 16 + (lane & 15);
        af[i] = *(const bf16x8*)((const char*)As + ra * 128 + (kb ^ ((ra & 7) << 4)));
      }
#pragma unroll
      for (int j = 0; j < 2; ++j) {
        int rb = wc * 32 + j * 16 + (lane & 15);
        bfr[j] = *(const bf16x8*)((const char*)Bs + rb * 128 + (kb ^ ((rb & 7) << 4)));
      }
#pragma unroll
      for (int i = 0; i < 4; ++i)
#pragma unroll
        for (int j = 0; j < 2; ++j)
          acc[i][j] = __builtin_amdgcn_mfma_f32_16x16x32_bf16(af[i], bfr[j], acc[i][j], 0, 0, 0);
    }
  }

  const int row0 = bm + wr * 64;
  const int col0 = bn + wc * 32;
#pragma unroll
  for (int i = 0; i < 4; ++i)
#pragma unroll
    for (int j = 0; j < 2; ++j) {
      int r = row0 + i * 16 + (lane >> 4) * 4;
      int ccol = col0 + j * 16 + (lane & 15);
#pragma unroll
      for (int q = 0; q < 4; ++q)
        Cout[(size_t)(r + q) * ND + ccol] = acc[i][j][q];
    }
}

// ---------------------------------------------------------------- V^T
// vraw bf16 [NM, ND] -> VT bf16 [B,H,Dh,S]
__global__ __launch_bounds__(256) void transv_kernel(
    const bf16* __restrict__ vraw, bf16* __restrict__ VT) {
  __shared__ bf16 tl[64][65];
  int s0 = blockIdx.x * 64;
  int bh = blockIdx.y;
  int b = bh >> 4, h = bh & 15;
  int t = threadIdx.x;
#pragma unroll
  for (int i = 0; i < 4; ++i) {
    int row = (t >> 4) + i * 16;
    int d4 = (t & 15) * 4;
    *(bf16x4*)&tl[row][d4] =
        *(const bf16x4*)&vraw[((size_t)(b * NS + s0 + row)) * ND + h * NDH + d4];
  }
  __syncthreads();
#pragma unroll
  for (int i = 0; i < 4; ++i) {
    int dr = (t >> 4) + i * 16;
    int s4 = (t & 15) * 4;
    bf16x4 o;
    o[0] = tl[s4 + 0][dr]; o[1] = tl[s4 + 1][dr];
    o[2] = tl[s4 + 2][dr]; o[3] = tl[s4 + 3][dr];
    *(bf16x4*)&VT[((size_t)(bh * NDH + dr)) * NS + s0 + s4] = o;
  }
}

// ---------------------------------------------------------------- attention
// Swapped-QK (mfma(K,Q)) in-register-softmax flash attention.
// LDS K/V staging, double-buffered, CHUNK-MAJOR layout [chunk][row][16B]:
// fragment ds_read_b128 is half-wave-contiguous -> 0 bank conflicts
// (row-major + XOR had 4.19M: 32 rows @ one 16B column is un-XOR-fixable).
// 4 waves x 32 q-rows, KVBLK=64.  Qr pre-scaled by 0.125*log2e -> exp2.
// Score C-layout: col=lane&31=query, row=(reg&3)+8*(reg>>2)+4*(lane>>5)=key.
__global__ __launch_bounds__(256, 2) void attn_kernel(
    const bf16* __restrict__ Qr, const bf16* __restrict__ Kr,
    const bf16* __restrict__ VT, bf16* __restrict__ out) {
  __shared__ bf16 Ks[2][512 * 8];   // [buf][chunk(8)*row(64)][8 elems] 8KB
  __shared__ bf16 Vs[2][512 * 8];
  const int t = threadIdx.x, lane = t & 63, w = t >> 6;
  const int hi = lane >> 5, ln = lane & 31;
  // XCD-bijective swizzle (512 blocks, 512%8==0): 4 bh per XCD -> K/V L2-resident
  int wg = blockIdx.x;
  int sw = (wg & 7) * 64 + (wg >> 3);
  const int qb = sw & 15, bh = sw >> 4;
  const int q0 = qb * 128 + w * 32;

  // Q fragment: B-operand, col=query=ln, k=d=(hi*8+e)+16c
  bf16x8 qv[4];
  {
    const bf16* Qb = Qr + ((size_t)bh * NS + q0 + ln) * NDH + hi * 8;
#pragma unroll
    for (int c = 0; c < 4; ++c) qv[c] = *(const bf16x8*)(Qb + c * 16);
  }

  f32x16 O0, O1;
#pragma unroll
  for (int r = 0; r < 16; ++r) { O0[r] = 0.f; O1[r] = 0.f; }
  float m = -1e30f, l = 0.f;

  // chunk-major stage: lds[ch*16B] <- row(ch&63), bytes [(ch>>6)*16 ..+16)
#define STAGE_KV(nb, kt2)                                                     \
  {                                                                           \
    _Pragma("unroll")                                                         \
    for (int i = 0; i < 2; ++i) {                                             \
      int ch = i * 256 + t;                                                   \
      int cp = ch >> 6, row = ch & 63;                                        \
      ASYNC16(Kr + ((size_t)bh * NS + (kt2) * 64 + row) * NDH + cp * 8,       \
              &Ks[nb][0] + ch * 8);                                           \
      ASYNC16(VT + ((size_t)bh * NDH + row) * NS + (kt2) * 64 + cp * 8,       \
              &Vs[nb][0] + ch * 8);                                           \
    }                                                                         \
  }

  STAGE_KV(0, 0);
  __syncthreads();

  int cur = 0;
  for (int kt = 0; kt < NS / 64; ++kt) {
    if (kt + 1 < NS / 64) STAGE_KV(cur ^ 1, kt + 1);
    const bf16* Kb = &Ks[cur][0];
    const bf16* Vb = &Vs[cur][0];

    // S = K Q^T (swapped): lane owns full 64-key row for query ln (pair lane^32)
    f32x16 s0, s1;
#pragma unroll
    for (int r = 0; r < 16; ++r) { s0[r] = 0.f; s1[r] = 0.f; }
    bf16x8 k0[4], k1[4];
#pragma unroll
    for (int c = 0; c < 4; ++c) {
      k0[c] = *(const bf16x8*)(Kb + (2 * c + hi) * 512 + ln * 8);
      k1[c] = *(const bf16x8*)(Kb + (2 * c + hi) * 512 + (32 + ln) * 8);
    }
    __builtin_amdgcn_s_setprio(1);
#pragma unroll
    for (int c = 0; c < 4; ++c) {
      s0 = __builtin_amdgcn_mfma_f32_32x32x16_bf16(k0[c], qv[c], s0, 0, 0, 0);
      s1 = __builtin_amdgcn_mfma_f32_32x32x16_bf16(k1[c], qv[c], s1, 0, 0, 0);
    }
    __builtin_amdgcn_s_setprio(0);

    // row max: pairwise tree + one half-swap
    float a0[8];
#pragma unroll
    for (int r = 0; r < 8; ++r) a0[r] = fmaxf(fmaxf(s0[r], s0[r + 8]), fmaxf(s1[r], s1[r + 8]));
    float b0 = fmaxf(fmaxf(a0[0], a0[1]), fmaxf(a0[2], a0[3]));
    float b1 = fmaxf(fmaxf(a0[4], a0[5]), fmaxf(a0[6], a0[7]));
    float pmax = fmaxf(b0, b1);
    pmax = fmaxf(pmax, __shfl_xor(pmax, 32, 64));

    // defer-max (T13): rescale only when max grew past threshold (log2 units)
    if (!__all(pmax - m <= 8.0f)) {
      float mnew = fmaxf(m, pmax);
      float scl = exp2f(m - mnew);
      m = mnew; l *= scl;
#pragma unroll
      for (int r = 0; r < 16; ++r) { O0[r] *= scl; O1[r] *= scl; }
    }

    // P = exp2(S - m), tree sum
    float p0[16], p1[16];
#pragma unroll
    for (int r = 0; r < 16; ++r) { p0[r] = exp2f(s0[r] - m); p1[r] = exp2f(s1[r] - m); }
    float sp[8];
#pragma unroll
    for (int r = 0; r < 8; ++r) sp[r] = (p0[r] + p0[r + 8]) + (p1[r] + p1[r + 8]);
    float sum = (((sp[0] + sp[1]) + (sp[2] + sp[3])) + ((sp[4] + sp[5]) + (sp[6] + sp[7])));
    sum += __shfl_xor(sum, 32, 64);
    l += sum;

    // P -> bf16 A-fragments in-register (T12): pack pairs, swap halves
    unsigned u0[8], u1[8], x0[8], x1[8];
#pragma unroll
    for (int g = 0; g < 4; ++g) {
      u0[g]     = cvt_pk_bf16(p0[4 * g],     p0[4 * g + 1]);
      u1[g]     = cvt_pk_bf16(p0[4 * g + 2], p0[4 * g + 3]);
      u0[4 + g] = cvt_pk_bf16(p1[4 * g],     p1[4 * g + 1]);
      u1[4 + g] = cvt_pk_bf16(p1[4 * g + 2], p1[4 * g + 3]);
    }
#pragma unroll
    for (int g = 0; g < 8; ++g) {
      x0[g] = __shfl_xor(u0[g], 32, 64);
      x1[g] = __shfl_xor(u1[g], 32, 64);
    }

    // O += P V   (A=P row=query, k=key; B=VT rows=d)
    bf16x8 v0[4], v1[4];
#pragma unroll
    for (int c = 0; c < 4; ++c) {
      v0[c] = *(const bf16x8*)(Vb + (2 * c + hi) * 512 + ln * 8);
      v1[c] = *(const bf16x8*)(Vb + (2 * c + hi) * 512 + (32 + ln) * 8);
    }
    __builtin_amdgcn_s_setprio(1);
#pragma unroll
    for (int c = 0; c < 4; ++c) {
      int base = (c >> 1) * 4 + (c & 1) * 2;   // kk*4 + even-group
      union { unsigned u[4]; bf16x8 v; } pa;
      pa.u[0] = hi ? x0[base + 1] : u0[base];
      pa.u[1] = hi ? x1[base + 1] : u1[base];
      pa.u[2] = hi ? u0[base + 1] : x0[base];
      pa.u[3] = hi ? u1[base + 1] : x1[base];
      O0 = __builtin_amdgcn_mfma_f32_32x32x16_bf16(pa.v, v0[c], O0, 0, 0, 0);
      O1 = __builtin_amdgcn_mfma_f32_32x32x16_bf16(pa.v, v1[c], O1, 0, 0, 0);
    }
    __builtin_amdgcn_s_setprio(0);

    __syncthreads();   // drains vmcnt (next-tile loads) + barrier
    cur ^= 1;
  }

  // epilogue: O row=query=(reg&3)+8*(reg>>2)+4*hi, col=d (O0: d=ln, O1: d=32+ln)
  float rl = 1.0f / l;
  const int b = bh >> 4, h = bh & 15;
#pragma unroll
  for (int r = 0; r < 16; ++r) {
    int q = (r & 3) + 8 * (r >> 2) + 4 * hi;
    float rlq = __shfl(rl, q, 64);
    int s = q0 + q;
    size_t base = ((size_t)(b * NS + s)) * ND + h * NDH + ln;
    out[base]      = (bf16)(O0[r] * rlq);
    out[base + 32] = (bf16)(O1[r] * rlq);
  }
}

// ---------------------------------------------------------------- launch
extern "C" void kernel_launch(void* const* d_in, const int* in_sizes, int n_in,
                              void* d_out, int out_size, void* d_ws, size_t ws_size,
                              hipStream_t stream) {
  const float* x  = (const float*)d_in[0];
  const float* wq = (const float*)d_in[1];
  const float* wk = (const float*)d_in[2];
  const float* wv = (const float*)d_in[3];
  const float* wo = (const float*)d_in[4];
  char* ws = (char*)d_ws;
  bf16* xb    = (bf16*)(ws);                     // 8MB [4096,1024]
  bf16* wb    = (bf16*)(ws + (8u << 20));        // 8MB Wq|Wk|Wv|Wo
  bf16* vraw  = (bf16*)(ws + (16u << 20));       // 8MB [4096,1024]
  bf16* Qr    = (bf16*)(ws + (24u << 20));       // 8MB [B,H,S,Dh] (pre-scaled)
  bf16* Kr    = (bf16*)(ws + (32u << 20));       // 8MB [B,H,S,Dh]
  bf16* VT    = (bf16*)(ws + (40u << 20));       // 8MB [B,H,Dh,S]
  bf16* attnb = (bf16*)(ws + (48u << 20));       // 8MB [B,S,H*Dh]
  float2* tab = (float2*)(ws + (56u << 20));     // 512KB [2048][32]
  float* out  = (float*)d_out;

  convert_kernel<<<8192, 256, 0, stream>>>(x, wq, wk, wv, wo, xb, wb);
  tab_kernel<<<256, 256, 0, stream>>>(tab);
  gemm_qkv<<<dim3(8, 32, 3), 256, 0, stream>>>(xb, wb, Qr, Kr, vraw, tab);
  transv_kernel<<<dim3(32, 32), 256, 0, stream>>>(vraw, VT);
  attn_kernel<<<dim3(512), 256, 0, stream>>>(Qr, Kr, VT, attnb);
  gemm_out<<<dim3(16, 32), 256, 0, stream>>>(attnb, wb + 3 * ND * ND, out);
}